// Round 3
// baseline (948.190 us; speedup 1.0000x reference)
//
#include <hip/hip_runtime.h>
#include <hip/hip_bf16.h>

#define NSPH 7

typedef short bf16x8 __attribute__((ext_vector_type(8)));
typedef float f32x4 __attribute__((ext_vector_type(4)));

static __device__ __forceinline__ ushort f2b(float f) {
    union { __hip_bfloat16 h; ushort u; } v; v.h = __float2bfloat16(f); return v.u;
}
static __device__ __forceinline__ float b2f(ushort u) {
    union { unsigned int i; float f; } v; v.i = ((unsigned int)u) << 16; return v.f;
}
static __device__ __forceinline__ float silu_f(float v) {
    return v / (1.0f + __expf(-v));
}
// load 8 consecutive f32 from p, round to bf16x8
static __device__ __forceinline__ bf16x8 ld8_f32_to_bf16(const float* p) {
    float4 p0 = *(const float4*)p;
    float4 p1 = *(const float4*)(p + 4);
    bf16x8 r;
    r[0] = (short)f2b(p0.x); r[1] = (short)f2b(p0.y);
    r[2] = (short)f2b(p0.z); r[3] = (short)f2b(p0.w);
    r[4] = (short)f2b(p1.x); r[5] = (short)f2b(p1.y);
    r[6] = (short)f2b(p1.z); r[7] = (short)f2b(p1.w);
    return r;
}

// ---------------------------------------------------------------------------
// K1: X[E,64] = silu(edge[E,128] @ W_down[64,128]^T), X stored bf16.
// 4 waves/block; wave w covers rows [blk*128 + w*32, +32), all 64 cols.
// ---------------------------------------------------------------------------
__launch_bounds__(256)
__global__ void k1_down(const float* __restrict__ edge, const float* __restrict__ Wd,
                        ushort* __restrict__ X) {
    const int tid  = threadIdx.x;
    const int lane = tid & 63;
    const int w    = tid >> 6;
    const int quad = lane >> 4;
    const int m16  = lane & 15;
    const int r0   = blockIdx.x * 128 + w * 32;

    f32x4 acc[2][4];
#pragma unroll
    for (int mi = 0; mi < 2; mi++)
#pragma unroll
        for (int ni = 0; ni < 4; ni++) acc[mi][ni] = (f32x4){0.f, 0.f, 0.f, 0.f};

#pragma unroll
    for (int k = 0; k < 128; k += 32) {
        bf16x8 a[2], b[4];
#pragma unroll
        for (int mi = 0; mi < 2; mi++)
            a[mi] = ld8_f32_to_bf16(&edge[(size_t)(r0 + mi * 16 + m16) * 128 + k + quad * 8]);
#pragma unroll
        for (int ni = 0; ni < 4; ni++)
            b[ni] = ld8_f32_to_bf16(&Wd[(ni * 16 + m16) * 128 + k + quad * 8]);
#pragma unroll
        for (int mi = 0; mi < 2; mi++)
#pragma unroll
            for (int ni = 0; ni < 4; ni++)
                acc[mi][ni] = __builtin_amdgcn_mfma_f32_16x16x32_bf16(a[mi], b[ni], acc[mi][ni], 0, 0, 0);
    }
#pragma unroll
    for (int mi = 0; mi < 2; mi++)
#pragma unroll
        for (int ni = 0; ni < 4; ni++)
#pragma unroll
            for (int r = 0; r < 4; r++) {
                int row = r0 + mi * 16 + quad * 4 + r;
                int col = ni * 16 + m16;
                X[(size_t)row * 64 + col] = f2b(silu_f(acc[mi][ni][r]));
            }
}

// ---------------------------------------------------------------------------
// K2: one wave per triplet iteration:
//   s[lane] = (W_sbf @ W_sbf0)[lane,:] . sbf[t,:]      (f32, wc in registers)
//   atomicAdd(out[ji[t]*128 + lane], b2f(X[kj[t]*64+lane]) * s[lane])
// agg[r] lives interleaved in out rows: out[r*128 + 0..63].
// ---------------------------------------------------------------------------
__launch_bounds__(256)
__global__ void k2_scatter(const int* __restrict__ kj, const int* __restrict__ ji,
                           const float* __restrict__ sbf, const ushort* __restrict__ X,
                           const float* __restrict__ Wsbf, const float* __restrict__ Wsbf0,
                           float* agg_out, int T) {
    const int lane = threadIdx.x & 63;
    float wj[NSPH], wc[NSPH];
#pragma unroll
    for (int i = 0; i < NSPH; i++) wj[i] = Wsbf[lane * NSPH + i];
#pragma unroll
    for (int k = 0; k < NSPH; k++) {
        float a = 0.f;
#pragma unroll
        for (int i = 0; i < NSPH; i++) a += wj[i] * Wsbf0[i * NSPH + k];
        wc[k] = a;
    }
    int gw = (blockIdx.x * 256 + threadIdx.x) >> 6;
    int nw = (gridDim.x * 256) >> 6;
    for (int t = gw; t < T; t += nw) {
        int a = kj[t];
        int b = ji[t];
        float s = 0.f;
#pragma unroll
        for (int k = 0; k < NSPH; k++) s += wc[k] * sbf[(size_t)t * NSPH + k];
        float val = b2f(X[(size_t)a * 64 + lane]) * s;
        unsafeAtomicAdd(&agg_out[(size_t)b * 128 + lane], val);
    }
}

// ---------------------------------------------------------------------------
// K3 (fused), per 128-row block:
//   GEMM1: Utile[128,128] = silu(agg_tile[128,64] @ W_up[128,64]^T) -> LDS bf16
//          (agg read from out rows, cols 0..63 — block-local)
//   GEMM2: out = silu([edge_tile | Utile] @ W_e1[128,256]^T + b) + edge_tile
// ---------------------------------------------------------------------------
__launch_bounds__(256)
__global__ void k3_fused(const float* __restrict__ edge, const float* __restrict__ Wu,
                         const float* __restrict__ We, const float* __restrict__ bias,
                         float* out) {
    __shared__ __align__(16) short Ut[128 * 136];
    const int tid  = threadIdx.x;
    const int lane = tid & 63;
    const int w    = tid >> 6;
    const int quad = lane >> 4;
    const int m16  = lane & 15;
    const int r0   = blockIdx.x * 128;
    const int rowbase = (w >> 1) * 64;
    const int colbase = (w & 1) * 64;

    // ---- GEMM1 ----
    f32x4 acc1[4][4];
#pragma unroll
    for (int mi = 0; mi < 4; mi++)
#pragma unroll
        for (int ni = 0; ni < 4; ni++) acc1[mi][ni] = (f32x4){0.f, 0.f, 0.f, 0.f};

#pragma unroll
    for (int kk = 0; kk < 64; kk += 32) {
        bf16x8 a[4], b[4];
#pragma unroll
        for (int mi = 0; mi < 4; mi++)
            a[mi] = ld8_f32_to_bf16(&out[(size_t)(r0 + rowbase + mi * 16 + m16) * 128 + kk + quad * 8]);
#pragma unroll
        for (int ni = 0; ni < 4; ni++)
            b[ni] = ld8_f32_to_bf16(&Wu[(colbase + ni * 16 + m16) * 64 + kk + quad * 8]);
#pragma unroll
        for (int mi = 0; mi < 4; mi++)
#pragma unroll
            for (int ni = 0; ni < 4; ni++)
                acc1[mi][ni] = __builtin_amdgcn_mfma_f32_16x16x32_bf16(a[mi], b[ni], acc1[mi][ni], 0, 0, 0);
    }
#pragma unroll
    for (int mi = 0; mi < 4; mi++)
#pragma unroll
        for (int ni = 0; ni < 4; ni++)
#pragma unroll
            for (int r = 0; r < 4; r++) {
                int rl = rowbase + mi * 16 + quad * 4 + r;
                int cl = colbase + ni * 16 + m16;
                Ut[rl * 136 + cl] = (short)f2b(silu_f(acc1[mi][ni][r]));
            }
    __syncthreads();

    // ---- GEMM2 ----
    f32x4 acc2[4][4];
#pragma unroll
    for (int mi = 0; mi < 4; mi++)
#pragma unroll
        for (int ni = 0; ni < 4; ni++) acc2[mi][ni] = (f32x4){0.f, 0.f, 0.f, 0.f};

#pragma unroll
    for (int k = 0; k < 256; k += 32) {
        bf16x8 a[4], b[4];
#pragma unroll
        for (int mi = 0; mi < 4; mi++) {
            int rl = rowbase + mi * 16 + m16;
            if (k < 128)
                a[mi] = ld8_f32_to_bf16(&edge[(size_t)(r0 + rl) * 128 + k + quad * 8]);
            else
                a[mi] = *(const bf16x8*)&Ut[rl * 136 + (k - 128) + quad * 8];
        }
#pragma unroll
        for (int ni = 0; ni < 4; ni++)
            b[ni] = ld8_f32_to_bf16(&We[(size_t)(colbase + ni * 16 + m16) * 256 + k + quad * 8]);
#pragma unroll
        for (int mi = 0; mi < 4; mi++)
#pragma unroll
            for (int ni = 0; ni < 4; ni++)
                acc2[mi][ni] = __builtin_amdgcn_mfma_f32_16x16x32_bf16(a[mi], b[ni], acc2[mi][ni], 0, 0, 0);
    }

#pragma unroll
    for (int mi = 0; mi < 4; mi++)
#pragma unroll
        for (int ni = 0; ni < 4; ni++) {
            int col = colbase + ni * 16 + m16;
            float bcol = bias[col];
#pragma unroll
            for (int r = 0; r < 4; r++) {
                int row = r0 + rowbase + mi * 16 + quad * 4 + r;
                float pre = acc2[mi][ni][r] + bcol;
                out[(size_t)row * 128 + col] = silu_f(pre) + edge[(size_t)row * 128 + col];
            }
        }
}

// ---------------------------------------------------------------------------
extern "C" void kernel_launch(void* const* d_in, const int* in_sizes, int n_in,
                              void* d_out, int out_size, void* d_ws, size_t ws_size,
                              hipStream_t stream) {
    const float* edge  = (const float*)d_in[0];
    const float* sbf   = (const float*)d_in[1];
    const int*   idxkj = (const int*)d_in[2];
    const int*   idxji = (const int*)d_in[3];
    const float* Wsbf0 = (const float*)d_in[4];
    const float* Wsbf  = (const float*)d_in[5];
    const float* We1   = (const float*)d_in[6];
    const float* be1   = (const float*)d_in[7];
    const float* Wdown = (const float*)d_in[8];
    const float* Wup   = (const float*)d_in[9];

    const int E = in_sizes[0] / 128;
    const int T = in_sizes[2];

    ushort* X   = (ushort*)d_ws;   // E*64 bf16 = 33.5 MB (only ws use)
    float*  out = (float*)d_out;   // E*128 f32; agg aliased at out[r*128 + 0..63]

    hipMemsetAsync(d_out, 0, (size_t)out_size * sizeof(float), stream);
    k1_down<<<E / 128, 256, 0, stream>>>(edge, Wdown, X);
    k2_scatter<<<8192, 256, 0, stream>>>(idxkj, idxji, sbf, X, Wsbf, Wsbf0, out, T);
    k3_fused<<<E / 128, 256, 0, stream>>>(edge, Wup, We1, be1, out);
}